// Round 1
// baseline (615.785 us; speedup 1.0000x reference)
//
#include <hip/hip_runtime.h>
#include <hip/hip_bf16.h>

// Problem constants: B=65536, A=8, E=128, K=2E=256
typedef __attribute__((ext_vector_type(8))) short short8;   // 8 bf16 = 4 VGPRs
typedef __attribute__((ext_vector_type(4))) float floatx4;  // MFMA accumulator

__device__ inline short f2bf(float f) {
  // round-to-nearest-even fp32 -> bf16 (no NaN handling needed: inputs are finite)
  unsigned u = __builtin_bit_cast(unsigned, f);
  unsigned r = u + 0x7fffu + ((u >> 16) & 1u);
  return (short)(r >> 16);
}

__device__ inline short8 cvt8(float4 a, float4 b) {
  short8 r;
  r[0] = f2bf(a.x); r[1] = f2bf(a.y); r[2] = f2bf(a.z); r[3] = f2bf(a.w);
  r[4] = f2bf(b.x); r[5] = f2bf(b.y); r[6] = f2bf(b.z); r[7] = f2bf(b.w);
  return r;
}

// ---------------------------------------------------------------------------
// Phase 1: fold W_agg into proj.
//   Mt[a][j][k] = sum_i W_agg[i][k] * proj[a][i][j]   (bf16, transposed so the
//                 GEMM's B-fragment reads are k-contiguous)
//   bias2[a][j] = sum_i b_agg[i] * proj[a][i][j]       (fp32)
// grid = A*E = 1024 blocks, 256 threads (one thread per k).
// ---------------------------------------------------------------------------
__global__ __launch_bounds__(256) void prep_M(
    const float* __restrict__ W, const float* __restrict__ proj,
    const float* __restrict__ bvec, short* __restrict__ Mt,
    float* __restrict__ bias2) {
  int blk = blockIdx.x;
  int a = blk >> 7, j = blk & 127;
  int k = threadIdx.x;  // 0..255
  const float* pj = proj + a * 16384 + j;  // proj[a][i][j], stride 128
  float acc = 0.f;
#pragma unroll 4
  for (int i = 0; i < 128; ++i)
    acc += W[i * 256 + k] * pj[i * 128];  // W coalesced over k, proj broadcast
  Mt[a * 32768 + j * 256 + k] = f2bf(acc);
  if (k == 0) {
    float b = 0.f;
    for (int i = 0; i < 128; ++i) b += bvec[i] * pj[i * 128];
    bias2[a * 128 + j] = b;
  }
}

// ---------------------------------------------------------------------------
// Phase 2: out[b,a,j] = [img[b,:] | edge[b,a,:]] @ Mt[a]^T + bias2[a,:]
//
// LDS-FREE version. Rationale (rocprof): HBM traffic already at the 544 MB
// floor, but BW stuck at 3.16/6.3 TB/s with MfmaUtil 8% / VALUBusy 11% /
// Occ 31% -> latency-bound on the barrier-drained stage pipeline. Each wave's
// MFMA fragments are directly loadable from global with full 128B-line
// coverage (4 quads x 16 lanes cover whole lines), and Mt[a] (64 KB/block,
// 512 KB total) is L2-resident. So: no LDS, no __syncthreads, fragments
// straight to registers, fp32->bf16 in-reg, K-loop fully unrolled so the
// compiler pipelines global loads across MFMA with counted waitcnts.
// 256 threads = 4 waves in a 2x2 grid, each wave a 64x64 output tile
// (4x4 MFMA tiles of 16x16x32). A is read twice per block (wm-paired waves)
// -> same-block L2 hit, no extra HBM fetch.
// ---------------------------------------------------------------------------
__global__ __launch_bounds__(256, 3) void gemm_main(
    const float* __restrict__ img, const float* __restrict__ edge,
    const short* __restrict__ Mt, const float* __restrict__ bias2,
    float* __restrict__ out) {
  const int tid = threadIdx.x;
  const int a = blockIdx.x & 7;          // attribute type -> spreads over XCDs
  const int b0 = (blockIdx.x >> 3) << 7; // batch-tile base
  const int wave = tid >> 6, lane = tid & 63;
  const int quad = lane >> 4, l16 = lane & 15;
  const int wm = wave & 1, wn = wave >> 1;

  floatx4 acc[4][4] = {};

  // Per-lane fragment base pointers (compile-time-constant indexed after
  // unroll -> stay in registers, not scratch).
  const float* imgB[4];
  const float* edgeB[4];
  const short* mB[4];
#pragma unroll
  for (int mt = 0; mt < 4; ++mt) {
    int row = b0 + wm * 64 + mt * 16 + l16;
    imgB[mt]  = img  + (size_t)row * 128  + quad * 8;
    edgeB[mt] = edge + (size_t)row * 1024 + a * 128 + quad * 8;
  }
  const short* Mta = Mt + a * 32768;
#pragma unroll
  for (int nt = 0; nt < 4; ++nt)
    mB[nt] = Mta + (wn * 64 + nt * 16 + l16) * 256 + quad * 8;

#pragma unroll
  for (int ks = 0; ks < 8; ++ks) {
    // A fragment: lane (quad,l16) holds A[m=l16][k = quad*8 .. quad*8+7]
    // ks<4 -> img half of the concat, ks>=4 -> edge half (uniform select).
    float4 v0[4], v1[4];
    short8 bfr[4];
#pragma unroll
    for (int mt = 0; mt < 4; ++mt) {
      const float* s = (ks < 4) ? (imgB[mt] + ks * 32)
                                : (edgeB[mt] + (ks - 4) * 32);
      v0[mt] = *(const float4*)s;
      v1[mt] = *(const float4*)(s + 4);
    }
    // B fragment: lane (quad,l16) holds Mt[a][n=l16][k = quad*8 ..] (bf16,
    // k-contiguous by construction of Mt). L2-resident.
#pragma unroll
    for (int nt = 0; nt < 4; ++nt)
      bfr[nt] = *(const short8*)(mB[nt] + ks * 32);

    short8 af[4];
#pragma unroll
    for (int mt = 0; mt < 4; ++mt) af[mt] = cvt8(v0[mt], v1[mt]);

#pragma unroll
    for (int mt = 0; mt < 4; ++mt)
#pragma unroll
      for (int nt = 0; nt < 4; ++nt)
        acc[mt][nt] = __builtin_amdgcn_mfma_f32_16x16x32_bf16(
            af[mt], bfr[nt], acc[mt][nt], 0, 0, 0);
  }

  // --- epilogue: C/D layout col=lane&15, row=quad*4+reg ---
  float bias[4];
#pragma unroll
  for (int nt = 0; nt < 4; ++nt)
    bias[nt] = bias2[a * 128 + wn * 64 + nt * 16 + l16];
#pragma unroll
  for (int mt = 0; mt < 4; ++mt)
#pragma unroll
    for (int nt = 0; nt < 4; ++nt) {
      int j = wn * 64 + nt * 16 + l16;
#pragma unroll
      for (int r = 0; r < 4; ++r) {
        int b = b0 + wm * 64 + mt * 16 + quad * 4 + r;
        out[(size_t)b * 1024 + a * 128 + j] = acc[mt][nt][r] + bias[nt];
      }
    }
}

extern "C" void kernel_launch(void* const* d_in, const int* in_sizes, int n_in,
                              void* d_out, int out_size, void* d_ws,
                              size_t ws_size, hipStream_t stream) {
  const float* img  = (const float*)d_in[0];  // [65536,128]
  const float* edge = (const float*)d_in[1];  // [65536,8,128]
  const float* W    = (const float*)d_in[2];  // [128,256]
  const float* bv   = (const float*)d_in[3];  // [128]
  const float* proj = (const float*)d_in[4];  // [8,128,128]
  float* out = (float*)d_out;                 // [65536,8,128]

  short* Mt = (short*)d_ws;                         // 8*128*256 bf16 = 512 KB
  float* bias2 = (float*)((char*)d_ws + 8 * 128 * 256 * 2);  // 4 KB

  prep_M<<<1024, 256, 0, stream>>>(W, proj, bv, Mt, bias2);
  gemm_main<<<4096, 256, 0, stream>>>(img, edge, Mt, bias2, out);
}

// Round 4
// 533.335 us; speedup vs baseline: 1.1546x; 1.1546x over previous
//
#include <hip/hip_runtime.h>
#include <hip/hip_bf16.h>

// Problem constants: B=65536, A=8, E=128, K=2E=256
typedef __attribute__((ext_vector_type(8))) short short8;   // 8 bf16 = 4 VGPRs
typedef __attribute__((ext_vector_type(4))) float floatx4;  // MFMA accumulator

__device__ inline short f2bf(float f) {
  // round-to-nearest-even fp32 -> bf16 (inputs finite; matches ref tolerance)
  unsigned u = __builtin_bit_cast(unsigned, f);
  unsigned r = u + 0x7fffu + ((u >> 16) & 1u);
  return (short)(r >> 16);
}

__device__ inline short8 cvt8(float4 a, float4 b) {
  short8 r;
  r[0] = f2bf(a.x); r[1] = f2bf(a.y); r[2] = f2bf(a.z); r[3] = f2bf(a.w);
  r[4] = f2bf(b.x); r[5] = f2bf(b.y); r[6] = f2bf(b.z); r[7] = f2bf(b.w);
  return r;
}

// ---------------------------------------------------------------------------
// Phase 1: fold W_agg into proj.
//   Mt[a][j][k] = sum_i W_agg[i][k] * proj[a][i][j]   (bf16, k-contiguous)
//   bias2[a][j] = sum_i b_agg[i] * proj[a][i][j]       (fp32)
// ---------------------------------------------------------------------------
__global__ __launch_bounds__(256) void prep_M(
    const float* __restrict__ W, const float* __restrict__ proj,
    const float* __restrict__ bvec, short* __restrict__ Mt,
    float* __restrict__ bias2) {
  int blk = blockIdx.x;
  int a = blk >> 7, j = blk & 127;
  int k = threadIdx.x;  // 0..255
  const float* pj = proj + a * 16384 + j;  // proj[a][i][j], stride 128
  float acc = 0.f;
#pragma unroll 4
  for (int i = 0; i < 128; ++i)
    acc += W[i * 256 + k] * pj[i * 128];
  Mt[a * 32768 + j * 256 + k] = f2bf(acc);
  if (k == 0) {
    float b = 0.f;
    for (int i = 0; i < 128; ++i) b += bvec[i] * pj[i * 128];
    bias2[a * 128 + j] = b;
  }
}

// ---------------------------------------------------------------------------
// Phase 2: out[b,a,j] = [img[b,:] | edge[b,a,:]] @ Mt[a]^T + bias2[a,:]
//
// v4 (plain HIP only — no global_load_lds, no inline asm; rounds 2/3 with the
// DMA path killed the container twice, rounds 0/1 without it ran fine):
//  * B (Mt[a], 64 KB, L2-hot per XCD since blk&7==a) read global->reg direct.
//  * A double-buffered in LDS as bf16 (2 x 10 KB, LDA=40 pad: read 2-way
//    bank alias only), ONE barrier per K-step (write buf[k&1] -> barrier ->
//    read buf[k&1]; next write to same buffer is 2 steps later).
//  * T14 reg-prefetch: global loads for step t+1 issued right after step t's
//    cvt consumed the regs -> HBM latency hides under barrier+B+ds_read+MFMA.
// ---------------------------------------------------------------------------
__global__ __launch_bounds__(256) void gemm_main(
    const float* __restrict__ img, const float* __restrict__ edge,
    const short* __restrict__ Mt, const float* __restrict__ bias2,
    float* __restrict__ out) {
  constexpr int LDA = 40;
  __shared__ short As[2][128 * LDA];  // [buf][row][32 bf16 (+8 pad)] = 2x10 KB

  const int tid = threadIdx.x;
  const int a = blockIdx.x & 7;          // attribute type == XCD -> Mt[a] L2-hot
  const int b0 = (blockIdx.x >> 3) << 7; // batch-tile base
  const int wave = tid >> 6, lane = tid & 63;
  const int quad = lane >> 4, l16 = lane & 15;
  const int wm = wave & 1, wn = wave >> 1;

  // --- A staging map: slot s=tid(+256) -> row=s>>2 (0..127), 8 floats at col
  // (s&3)*8. Thread handles rows r0 and r0+64, same column chunk. ---
  const int r0 = tid >> 2, c8 = tid & 3;
  const float* gImg0  = img  + (size_t)(b0 + r0) * 128 + c8 * 8;
  const float* gImg1  = gImg0 + 64 * 128;
  const float* gEdge0 = edge + (size_t)(b0 + r0) * 1024 + a * 128 + c8 * 8;
  const float* gEdge1 = gEdge0 + (size_t)64 * 1024;
  short* w0p = &As[0][r0 * LDA + c8 * 8];         // buf-0 write ptrs
  short* w1p = &As[0][(r0 + 64) * LDA + c8 * 8];
  constexpr int BUFS = 128 * LDA;                 // shorts per buffer

  // --- B fragment pointers (global, L2-resident) ---
  const short* mB[4];
#pragma unroll
  for (int nt = 0; nt < 4; ++nt)
    mB[nt] = Mt + a * 32768 + (wn * 64 + nt * 16 + l16) * 256 + quad * 8;

  // --- A fragment LDS read offsets ---
  int offA[4];
#pragma unroll
  for (int mt = 0; mt < 4; ++mt)
    offA[mt] = (wm * 64 + mt * 16 + l16) * LDA + quad * 8;

  floatx4 acc[4][4] = {};

  // prologue: load A(0) into regs
  float4 pa0 = *(const float4*)gImg0;
  float4 pa1 = *(const float4*)(gImg0 + 4);
  float4 pb0 = *(const float4*)gImg1;
  float4 pb1 = *(const float4*)(gImg1 + 4);

  for (int ks = 0; ks < 8; ++ks) {
    const int cur = ks & 1;
    // consume prefetch regs -> bf16 -> LDS buf[cur]
    short8 wa = cvt8(pa0, pa1);
    short8 wb = cvt8(pb0, pb1);
    *(short8*)(w0p + cur * BUFS) = wa;
    *(short8*)(w1p + cur * BUFS) = wb;

    // issue prefetch for step ks+1 (regs free now; latency hides under the
    // barrier + B loads + ds_reads + MFMA below)
    if (ks < 7) {
      const int nk = ks + 1;
      const float* s0 = (nk < 4) ? gImg0 + nk * 32 : gEdge0 + (nk - 4) * 32;
      const float* s1 = (nk < 4) ? gImg1 + nk * 32 : gEdge1 + (nk - 4) * 32;
      pa0 = *(const float4*)s0;
      pa1 = *(const float4*)(s0 + 4);
      pb0 = *(const float4*)s1;
      pb1 = *(const float4*)(s1 + 4);
    }

    __syncthreads();  // buf[cur] visible to all waves

    // B fragments from L2 (independent of LDS; issue before ds_reads)
    short8 bfr[4];
#pragma unroll
    for (int nt = 0; nt < 4; ++nt)
      bfr[nt] = *(const short8*)(mB[nt] + ks * 32);

    const short* Ab = As[0] + cur * BUFS;
#pragma unroll
    for (int mt = 0; mt < 4; ++mt) {
      short8 af = *(const short8*)(Ab + offA[mt]);
#pragma unroll
      for (int nt = 0; nt < 4; ++nt)
        acc[mt][nt] = __builtin_amdgcn_mfma_f32_16x16x32_bf16(
            af, bfr[nt], acc[mt][nt], 0, 0, 0);
    }
    // no trailing barrier: next iteration writes buf[cur^1]; the write to
    // buf[cur] recurs at ks+2, separated from this step's reads by the
    // barrier at ks+1.
  }

  // --- epilogue: C/D layout col=lane&15, row=quad*4+reg ---
  float bias[4];
#pragma unroll
  for (int nt = 0; nt < 4; ++nt)
    bias[nt] = bias2[a * 128 + wn * 64 + nt * 16 + l16];
#pragma unroll
  for (int mt = 0; mt < 4; ++mt)
#pragma unroll
    for (int nt = 0; nt < 4; ++nt) {
      int j = wn * 64 + nt * 16 + l16;
#pragma unroll
      for (int r = 0; r < 4; ++r) {
        int b = b0 + wm * 64 + mt * 16 + quad * 4 + r;
        out[(size_t)b * 1024 + a * 128 + j] = acc[mt][nt][r] + bias[nt];
      }
    }
}

extern "C" void kernel_launch(void* const* d_in, const int* in_sizes, int n_in,
                              void* d_out, int out_size, void* d_ws,
                              size_t ws_size, hipStream_t stream) {
  const float* img  = (const float*)d_in[0];  // [65536,128]
  const float* edge = (const float*)d_in[1];  // [65536,8,128]
  const float* W    = (const float*)d_in[2];  // [128,256]
  const float* bv   = (const float*)d_in[3];  // [128]
  const float* proj = (const float*)d_in[4];  // [8,128,128]
  float* out = (float*)d_out;                 // [65536,8,128]

  short* Mt = (short*)d_ws;                         // 8*128*256 bf16 = 512 KB
  float* bias2 = (float*)((char*)d_ws + 8 * 128 * 256 * 2);  // 4 KB

  prep_M<<<1024, 256, 0, stream>>>(W, proj, bv, Mt, bias2);
  gemm_main<<<4096, 256, 0, stream>>>(img, edge, Mt, bias2, out);
}